// Round 2
// baseline (155.900 us; speedup 1.0000x reference)
//
#include <hip/hip_runtime.h>
#include <math.h>

#define NB 64
#define NT 12
#define ND 256
#define NS 512
#define NV 512

// Module-scope intermediates (replaces d_ws): fully overwritten every
// invocation before any read, so no stale-state hazard across iterations.
// Round-1 retry: round-0 submission of this exact experiment hit a
// container-acquisition failure ("failed twice") with no compile/test error.
__device__ float g_gates[2 * NB * NT];   // [2][B*T]
__device__ float g_gs[NB * 512];         // [B][512]
__device__ float g_H[2 * NB * 256];      // [2][B][256]

__device__ __forceinline__ float gelu_exact(float x) {
    return 0.5f * x * (1.0f + erff(x * 0.70710678118654752f));
}
__device__ __forceinline__ float sigmoidf_(float x) {
    return 1.0f / (1.0f + __expf(-x));
}

// ---------------------------------------------------------------------------
// K1: gate MLPs. grid = (b(64) x gate(2) x t-half(2)) = 256 blocks,
// 1024 threads = (j 0..255) x (ih 0..3 : 64-row i-chunk). Full-chip, 16 waves
// per CU. Per-CU cost: L2 weight stream 256KB (~4.3K cyc) > VALU 3.1K cyc ->
// L2-BW bound ~2us. LDS reduce over ih, then j-reduction, sigmoid, store.
// ---------------------------------------------------------------------------
__global__ __launch_bounds__(1024) void k_gates(
    const float* __restrict__ evidence,
    const float* __restrict__ Wmg1, const float* __restrict__ bmg1,
    const float* __restrict__ Wmg2, const float* __restrict__ bmg2,
    const float* __restrict__ Wsg1, const float* __restrict__ bsg1,
    const float* __restrict__ Wsg2, const float* __restrict__ bsg2)
{
    const int blk = blockIdx.x;
    const int b  = blk >> 2;
    const int g  = (blk >> 1) & 1;
    const int th = blk & 1;
    const int t0 = th * 6;
    const int tid = threadIdx.x;
    const int j = tid & 255;
    const int ih = tid >> 8;           // 0..3
    const int lane = tid & 63, wv = tid >> 6;

    __shared__ float part[3][6][256];
    __shared__ float red[4][6];

    const float* __restrict__ W1 = g ? Wsg1 : Wmg1;
    const float* __restrict__ b1 = g ? bsg1 : bmg1;
    const float* __restrict__ W2 = g ? Wsg2 : Wmg2;
    const float* __restrict__ b2 = g ? bsg2 : bmg2;
    const float* __restrict__ ev = evidence + b * (NT * ND) + t0 * ND;

    float h[6];
    #pragma unroll
    for (int t = 0; t < 6; ++t) h[t] = 0.0f;

    const int ibase = ih * 64;
    #pragma unroll 8
    for (int ii = 0; ii < 64; ++ii) {
        const int i = ibase + ii;
        float w = W1[i * ND + j];
        #pragma unroll
        for (int t = 0; t < 6; ++t) h[t] += ev[t * ND + i] * w;
    }

    if (ih > 0) {
        #pragma unroll
        for (int t = 0; t < 6; ++t) part[ih - 1][t][j] = h[t];
    }
    __syncthreads();
    if (ih == 0) {
        const float b1j = b1[j], w2j = W2[j];
        #pragma unroll
        for (int t = 0; t < 6; ++t) {
            float v = gelu_exact(h[t] + part[0][t][j] + part[1][t][j] +
                                 part[2][t][j] + b1j) * w2j;
            #pragma unroll
            for (int off = 32; off > 0; off >>= 1) v += __shfl_down(v, off, 64);
            if (lane == 0) red[wv][t] = v;
        }
    }
    __syncthreads();
    if (tid < 6) {
        float s = red[0][tid] + red[1][tid] + red[2][tid] + red[3][tid] + b2[0];
        g_gates[g * (NB * NT) + b * NT + t0 + tid] = sigmoidf_(s);
    }
}

// ---------------------------------------------------------------------------
// K2: sparse graph readout. grid = 64 (block/batch), 512 threads. map/step
// memories never materialized (<=12 nonzeros each). Walk propagated by 12
// threads via LDS atomics; acc lists gathered split-half with 4-wide prefetch.
// ---------------------------------------------------------------------------
__global__ __launch_bounds__(512) void k_readout(
    const int* __restrict__ marker, const int* __restrict__ srci,
    const int* __restrict__ srcv, const int* __restrict__ tsymi,
    const int* __restrict__ tsymv, const int* __restrict__ tvali,
    const int* __restrict__ tvalv, const int* __restrict__ qidx,
    const int* __restrict__ qvld,
    const float* __restrict__ symbol_emb, const float* __restrict__ value_emb)
{
    const int b = blockIdx.x, tid = threadIdx.x;
    __shared__ float walk[NS], nxt[NS];
    __shared__ int   esrc[NT], etsym[NT], etval[NT];
    __shared__ float mapw[NT], stepw[NT];
    __shared__ int   sidx[64]; __shared__ float sval[64];
    __shared__ int   vidx[64]; __shared__ float vval[64];
    __shared__ int   scnt, vcnt;

    walk[tid] = 0.f; nxt[tid] = 0.f;
    if (tid == 0) { scnt = 0; vcnt = 0; }
    if (tid < NT) {
        int e = b * NT + tid;
        int mk = marker[e];
        int sv_ = srcv[e], tsv_ = tsymv[e], tvv_ = tvalv[e];
        esrc[tid]  = min(max(srci[e], 0), NS - 1);
        etsym[tid] = min(max(tsymi[e], 0), NS - 1);
        etval[tid] = min(max(tvali[e], 0), NV - 1);
        bool mmask = ((mk == 0) || (mk == 1)) && (sv_ > 0) && (tvv_ > 0);
        bool smask = (mk == 2) && (sv_ > 0) && (tsv_ > 0);
        mapw[tid]  = mmask ? g_gates[0 * (NB * NT) + e] : 0.f;
        stepw[tid] = smask ? g_gates[1 * (NB * NT) + e] : 0.f;
    }
    __syncthreads();
    if (tid == 0) {
        int qc = min(max(qidx[b], 0), NS - 1);
        float qv = (float)qvld[b];
        walk[qc] = qv;
        if (qv != 0.f) { sidx[0] = qc; sval[0] = qv; scnt = 1; }
    }
    __syncthreads();
    if (tid < NT) {   // stage 0: acc_v from initial walk
        float c = walk[esrc[tid]] * mapw[tid];
        if (c != 0.f) { int k = atomicAdd(&vcnt, 1); vidx[k] = etval[tid]; vval[k] = c; }
    }
    __syncthreads();
    for (int stp = 0; stp < 3; ++stp) {
        if (tid < NT) {
            float c = walk[esrc[tid]] * stepw[tid];
            if (c != 0.f) {
                atomicAdd(&nxt[etsym[tid]], c);
                int k = atomicAdd(&scnt, 1); sidx[k] = etsym[tid]; sval[k] = c;
            }
        }
        __syncthreads();
        { float a = nxt[tid]; walk[tid] = a; nxt[tid] = 0.f; }
        __syncthreads();
        if (tid < NT) {
            float c = walk[esrc[tid]] * mapw[tid];
            if (c != 0.f) { int k = atomicAdd(&vcnt, 1); vidx[k] = etval[tid]; vval[k] = c; }
        }
        __syncthreads();
    }
    const int d = tid & 255;
    const float* __restrict__ emb  = (tid < 256) ? symbol_emb : value_emb;
    const int*   idxl = (tid < 256) ? sidx : vidx;
    const float* vall = (tid < 256) ? sval : vval;
    const int n = (tid < 256) ? scnt : vcnt;
    float acc = 0.f;
    int k = 0;
    for (; k + 4 <= n; k += 4) {
        int   i0 = idxl[k],     i1 = idxl[k + 1], i2 = idxl[k + 2], i3 = idxl[k + 3];
        float w0 = vall[k],     w1 = vall[k + 1], w2 = vall[k + 2], w3 = vall[k + 3];
        float r0 = emb[i0 * ND + d], r1 = emb[i1 * ND + d];
        float r2 = emb[i2 * ND + d], r3 = emb[i3 * ND + d];
        acc += w0 * r0; acc += w1 * r1; acc += w2 * r2; acc += w3 * r3;
    }
    for (; k < n; ++k) acc += vall[k] * emb[idxl[k] * ND + d];
    g_gs[b * 512 + (tid < 256 ? 0 : 256) + d] = acc;
}

// ---------------------------------------------------------------------------
// K3: first MLP layers. grid = (2 mats x 4 j-slices x 8 b-tiles) = 64 blocks,
// 512 threads: i split across thread halves, LDS pair-reduce.
// ---------------------------------------------------------------------------
__global__ __launch_bounds__(512) void k_mlp1(
    const float* __restrict__ Wo1, const float* __restrict__ bo1,
    const float* __restrict__ Wf1, const float* __restrict__ bf1)
{
    const int blk = blockIdx.x;
    const int m = blk >> 5;
    const int r = blk & 31;
    const int js = r >> 3, bt = r & 7;
    const int tid = threadIdx.x;
    const int lane = tid & 63;
    const int bsub = (tid >> 6) & 3;
    const int ih = tid >> 8;
    const int j = js * 64 + lane;
    const int b0 = bt * 8 + bsub * 2, b1_ = b0 + 1;

    const float* __restrict__ W1   = (m ? Wf1 : Wo1) + ih * 256 * 256;
    const float* __restrict__ bias = m ? bf1 : bo1;
    const float* __restrict__ x0 = g_gs + b0 * 512 + ih * 256;
    const float* __restrict__ x1 = g_gs + b1_ * 512 + ih * 256;

    float a0 = 0.f, a1 = 0.f;
    #pragma unroll 8
    for (int i = 0; i < 256; ++i) {
        float w = W1[i * 256 + j];
        a0 += x0[i] * w; a1 += x1[i] * w;
    }
    __shared__ float part[256][2];
    if (ih == 1) { part[tid & 255][0] = a0; part[tid & 255][1] = a1; }
    __syncthreads();
    if (ih == 0) {
        float bj = bias[j];
        g_H[m * (NB * 256) + b0 * 256 + j]  = gelu_exact(a0 + part[tid][0] + bj);
        g_H[m * (NB * 256) + b1_ * 256 + j] = gelu_exact(a1 + part[tid][1] + bj);
    }
}

// ---------------------------------------------------------------------------
// K4: second MLP layers. blocks 0..63: logits (64x512); 64..95: feedback
// (64x256). 512 threads, k split across halves + LDS pair-reduce.
// ---------------------------------------------------------------------------
__global__ __launch_bounds__(512) void k_mlp2(
    const float* __restrict__ Wo2, const float* __restrict__ bo2,
    const float* __restrict__ Wf2, const float* __restrict__ bf2,
    float* __restrict__ out)  // [logits 64*512 | feedback 64*256]
{
    const int blk = blockIdx.x;
    const int tid = threadIdx.x;
    const int lane = tid & 63;
    const int bsub = (tid >> 6) & 3;
    const int ih = tid >> 8;
    __shared__ float part[256][2];

    if (blk < 64) {
        const int bt = blk >> 3, vs = blk & 7;
        const int v = vs * 64 + lane;
        const int b0 = bt * 8 + bsub * 2, b1_ = b0 + 1;
        const float* __restrict__ h0 = g_H + b0 * 256 + ih * 128;
        const float* __restrict__ h1 = g_H + b1_ * 256 + ih * 128;
        const float* __restrict__ Wp = Wo2 + ih * 128 * 512;
        float a0 = 0.f, a1 = 0.f;
        #pragma unroll 8
        for (int k = 0; k < 128; ++k) {
            float w = Wp[k * 512 + v];
            a0 += h0[k] * w; a1 += h1[k] * w;
        }
        if (ih == 1) { part[tid & 255][0] = a0; part[tid & 255][1] = a1; }
        __syncthreads();
        if (ih == 0) {
            float bv = bo2[v];
            out[b0 * 512 + v]  = a0 + part[tid][0] + bv;
            out[b1_ * 512 + v] = a1 + part[tid][1] + bv;
        }
    } else {
        const int r = blk - 64;
        const int bt = r >> 2, ds = r & 3;
        const int d = ds * 64 + lane;
        const int b0 = bt * 8 + bsub * 2, b1_ = b0 + 1;
        const float* __restrict__ h0 = g_H + (NB * 256) + b0 * 256 + ih * 128;
        const float* __restrict__ h1 = g_H + (NB * 256) + b1_ * 256 + ih * 128;
        const float* __restrict__ Wp = Wf2 + ih * 128 * 256;
        float a0 = 0.f, a1 = 0.f;
        #pragma unroll 8
        for (int k = 0; k < 128; ++k) {
            float w = Wp[k * 256 + d];
            a0 += h0[k] * w; a1 += h1[k] * w;
        }
        if (ih == 1) { part[tid & 255][0] = a0; part[tid & 255][1] = a1; }
        __syncthreads();
        if (ih == 0) {
            float bd = bf2[d];
            out[NB * NV + b0 * 256 + d]  = a0 + part[tid][0] + bd;
            out[NB * NV + b1_ * 256 + d] = a1 + part[tid][1] + bd;
        }
    }
}

extern "C" void kernel_launch(void* const* d_in, const int* in_sizes, int n_in,
                              void* d_out, int out_size, void* d_ws, size_t ws_size,
                              hipStream_t stream) {
    const int* event_marker       = (const int*)d_in[0];
    const int* source_idx         = (const int*)d_in[1];
    const int* source_valid       = (const int*)d_in[2];
    const int* target_symbol_idx  = (const int*)d_in[3];
    const int* target_symbol_vld  = (const int*)d_in[4];
    const int* target_value_idx   = (const int*)d_in[5];
    const int* target_value_vld   = (const int*)d_in[6];
    const int* query_idx          = (const int*)d_in[7];
    const int* query_valid        = (const int*)d_in[8];
    const float* evidence   = (const float*)d_in[9];
    const float* symbol_emb = (const float*)d_in[10];
    const float* value_emb  = (const float*)d_in[11];
    const float* Wmg1 = (const float*)d_in[12]; const float* bmg1 = (const float*)d_in[13];
    const float* Wmg2 = (const float*)d_in[14]; const float* bmg2 = (const float*)d_in[15];
    const float* Wsg1 = (const float*)d_in[16]; const float* bsg1 = (const float*)d_in[17];
    const float* Wsg2 = (const float*)d_in[18]; const float* bsg2 = (const float*)d_in[19];
    const float* Wf1  = (const float*)d_in[20]; const float* bf1  = (const float*)d_in[21];
    const float* Wf2  = (const float*)d_in[22]; const float* bf2  = (const float*)d_in[23];
    const float* Wo1  = (const float*)d_in[24]; const float* bo1  = (const float*)d_in[25];
    const float* Wo2  = (const float*)d_in[26]; const float* bo2  = (const float*)d_in[27];

    (void)d_ws; (void)ws_size;  // experiment: workspace untouched (see theory)

    k_gates<<<dim3(256), dim3(1024), 0, stream>>>(
        evidence, Wmg1, bmg1, Wmg2, bmg2, Wsg1, bsg1, Wsg2, bsg2);
    k_readout<<<dim3(64), dim3(512), 0, stream>>>(
        event_marker, source_idx, source_valid, target_symbol_idx,
        target_symbol_vld, target_value_idx, target_value_vld,
        query_idx, query_valid, symbol_emb, value_emb);
    k_mlp1<<<dim3(64), dim3(512), 0, stream>>>(Wo1, bo1, Wf1, bf1);
    k_mlp2<<<dim3(96), dim3(512), 0, stream>>>(Wo2, bo2, Wf2, bf2, (float*)d_out);
}